// Round 11
// baseline (278.893 us; speedup 1.0000x reference)
//
#include <hip/hip_runtime.h>
#include <hip/hip_bf16.h>
#include <stdint.h>

#define NN 50000
#define NE 800000
#define NB 196            // dst buckets: dst>>8 (256 nodes each)
#define EPB 2048
#define NBLK ((NE + EPB - 1) / EPB)   // 391

typedef __attribute__((ext_vector_type(8))) __bf16 bf16x8;
typedef __attribute__((ext_vector_type(4))) float f32x4;

__device__ __forceinline__ float bflo(uint32_t u) { return __uint_as_float(u << 16); }
__device__ __forceinline__ float bfhi(uint32_t u) { return __uint_as_float(u & 0xffff0000u); }
__device__ __forceinline__ uint16_t f2bf(float f) {
    uint32_t u = __float_as_uint(f);
    u += 0x7fffu + ((u >> 16) & 1u);   // RNE
    return (uint16_t)(u >> 16);
}
__device__ __forceinline__ float bf2f(uint16_t h) { return __uint_as_float(((uint32_t)h) << 16); }

// ---------------- dtype detection ----------------
__global__ __launch_bounds__(256) void detect(const uint32_t* __restrict__ xu,
                                              const int* __restrict__ ei,
                                              int* __restrict__ flags) {
    __shared__ int cnt_f, cnt_i;
    if (threadIdx.x == 0) { cnt_f = 0; cnt_i = 0; }
    __syncthreads();
    uint32_t u = xu[threadIdx.x];
    uint32_t lo = u & 0xffffu;
    uint32_t e = (lo >> 7) & 0xffu;
    int ok = (lo == 0u) || (e >= 96u && e <= 150u);
    atomicAdd(&cnt_f, ok);
    if (threadIdx.x < 64) {
        int w = ei[2 * threadIdx.x + 1];
        atomicAdd(&cnt_i, (w != 0) ? 1 : 0);
    }
    __syncthreads();
    if (threadIdx.x == 0) {
        flags[0] = (cnt_f < 192) ? 1 : 0;
        flags[1] = (cnt_i < 4) ? 1 : 0;
    }
}

// ---------------- pass 1: per-block bucket histograms (LDS atomics only) ----------------
__global__ __launch_bounds__(256) void hist_pass(const int* __restrict__ ei, const int* __restrict__ flags,
                                                 int* __restrict__ histM) {
    __shared__ int hist[NB];
    for (int i = threadIdx.x; i < NB; i += 256) hist[i] = 0;
    __syncthreads();
    int base = blockIdx.x * EPB;
    int fl = flags[1];
    for (int i = 0; i < EPB; i += 256) {
        int e = base + i + threadIdx.x;
        if (e < NE) {
            int d = fl ? ei[2 * NE + 2 * e] : ei[NE + e];
            atomicAdd(&hist[d >> 8], 1);
        }
    }
    __syncthreads();
    for (int i = threadIdx.x; i < NB; i += 256) histM[i * NBLK + blockIdx.x] = hist[i];
}

// ---------------- pass 2a: per-bucket scan over block counts ----------------
__global__ __launch_bounds__(512) void scan_rows(int* __restrict__ histM, int* __restrict__ bucket_tot) {
    __shared__ int sm[512];
    int b = blockIdx.x, t = threadIdx.x;
    int v = (t < NBLK) ? histM[b * NBLK + t] : 0;
    sm[t] = v;
    __syncthreads();
    for (int o = 1; o < 512; o <<= 1) {
        int x = (t >= o) ? sm[t - o] : 0;
        __syncthreads();
        sm[t] += x;
        __syncthreads();
    }
    if (t < NBLK) histM[b * NBLK + t] = sm[t] - v;   // exclusive prefix in-place
    if (t == 511) bucket_tot[b] = sm[511];
}

// ---------------- pass 2b: scan bucket totals -> bucket bases ----------------
__global__ __launch_bounds__(256) void scan_tot(const int* __restrict__ bucket_tot, int* __restrict__ bucket_base) {
    __shared__ int sm[256];
    int t = threadIdx.x;
    int v = (t < NB) ? bucket_tot[t] : 0;
    sm[t] = v;
    __syncthreads();
    for (int o = 1; o < 256; o <<= 1) {
        int x = (t >= o) ? sm[t - o] : 0;
        __syncthreads();
        sm[t] += x;
        __syncthreads();
    }
    if (t < NB) bucket_base[t] = sm[t] - v;
    if (t == 0) bucket_base[NB] = NE;
}

// ---------------- pass 3: scatter edges into reserved bucket runs ----------------
// staging entry: (dst&0xff)<<16 | src   (NN < 2^16)
__global__ __launch_bounds__(256) void scatter_pass(const int* __restrict__ ei, const int* __restrict__ flags,
                                                    const int* __restrict__ histM, const int* __restrict__ bucket_base,
                                                    uint32_t* __restrict__ staging) {
    __shared__ int curs[NB];
    int blk = blockIdx.x, t = threadIdx.x;
    for (int i = t; i < NB; i += 256) curs[i] = bucket_base[i] + histM[i * NBLK + blk];
    __syncthreads();
    int base = blk * EPB;
    int fl = flags[1];
    for (int i = 0; i < EPB; i += 256) {
        int e = base + i + t;
        if (e < NE) {
            int s, d;
            if (fl) { s = ei[2 * e]; d = ei[2 * NE + 2 * e]; }
            else    { s = ei[e];     d = ei[NE + e]; }
            int p = atomicAdd(&curs[d >> 8], 1);
            staging[p] = ((uint32_t)(d & 0xff) << 16) | (uint32_t)s;
        }
    }
}

// ---------------- pass 4: per-bucket CSR build, bookkeeping in LDS ----------------
__global__ __launch_bounds__(256) void build_csr(const uint32_t* __restrict__ staging,
                                                 const int* __restrict__ bucket_base,
                                                 int* __restrict__ row_start, int* __restrict__ deg,
                                                 float* __restrict__ inv_deg, int* __restrict__ csr) {
    __shared__ int degs[256];
    __shared__ int sm[256];
    __shared__ int curs[256];
    int b = blockIdx.x, t = threadIdx.x;
    int beg = bucket_base[b], cnt = bucket_base[b + 1] - beg;
    degs[t] = 0;
    __syncthreads();
    for (int i = t; i < cnt; i += 256) atomicAdd(&degs[(staging[beg + i] >> 16) & 0xff], 1);
    __syncthreads();
    int d = degs[t];
    sm[t] = d;
    __syncthreads();
    for (int o = 1; o < 256; o <<= 1) {
        int x = (t >= o) ? sm[t - o] : 0;
        __syncthreads();
        sm[t] += x;
        __syncthreads();
    }
    int excl = sm[t] - d;
    curs[t] = excl;
    int node = b * 256 + t;
    if (node < NN) {
        row_start[node] = beg + excl;
        deg[node] = d;
        inv_deg[node] = 1.0f / (float)(d > 0 ? d : 1);
    }
    __syncthreads();
    for (int i = t; i < cnt; i += 256) {
        uint32_t u = staging[beg + i];
        int dl = (u >> 16) & 0xff;
        int p = atomicAdd(&curs[dl], 1);
        csr[beg + p] = (int)(u & 0xffffu);
    }
}

__global__ __launch_bounds__(256) void norm_x(const void* __restrict__ x, const int* __restrict__ flags,
                                              uint32_t* __restrict__ out) {
    int i = blockIdx.x * 256 + threadIdx.x;  // < NN*64
    if (flags[0]) {
        float2 v = ((const float2*)x)[i];
        out[i] = (uint32_t)f2bf(v.x) | ((uint32_t)f2bf(v.y) << 16);
    } else {
        out[i] = ((const uint32_t*)x)[i];
    }
}

// ---------------- weights: normalize + swizzle into B-fragment layout ----------------
__global__ __launch_bounds__(256) void norm_weights_sw(const void* __restrict__ w1l, const void* __restrict__ b1,
                                                       const void* __restrict__ w1r, const void* __restrict__ w2l,
                                                       const void* __restrict__ b2, const void* __restrict__ w2r,
                                                       const int* __restrict__ flags,
                                                       uint16_t* __restrict__ w1l_sw, uint16_t* __restrict__ w1r_sw,
                                                       uint16_t* __restrict__ w2l_sw, uint16_t* __restrict__ w2r_sw,
                                                       uint16_t* __restrict__ bias_buf) {
    int tid = blockIdx.x * 256 + threadIdx.x;
    int fp32 = flags[0];
    if (tid < 16384) {
        int frag = tid >> 6, lane = tid & 63;
        const void* srcw; uint16_t* dst; int N; int fl;
        if (frag < 64)       { srcw = w1l; dst = w1l_sw; N = 256; fl = frag; }
        else if (frag < 128) { srcw = w1r; dst = w1r_sw; N = 256; fl = frag - 64; }
        else if (frag < 192) { srcw = w2l; dst = w2l_sw; N = 128; fl = frag - 128; }
        else                 { srcw = w2r; dst = w2r_sw; N = 128; fl = frag - 192; }
        int NTm = N >> 4;
        int kt = fl / NTm, nt = fl - kt * NTm;
        int k0 = kt * 32 + (lane >> 4) * 8, n = nt * 16 + (lane & 15);
        uint16_t* d = dst + (size_t)fl * 512 + lane * 8;
#pragma unroll
        for (int j = 0; j < 8; j++) {
            int si = (k0 + j) * N + n;
            d[j] = fp32 ? f2bf(((const float*)srcw)[si]) : ((const uint16_t*)srcw)[si];
        }
    } else if (tid < 16384 + 384) {
        int j = tid - 16384;
        const void* s = (j < 256) ? b1 : b2;
        int jj = (j < 256) ? j : j - 256;
        bias_buf[j] = fp32 ? f2bf(((const float*)s)[jj]) : ((const uint16_t*)s)[jj];
    }
}

// ---------------- mean aggregation: 2 nodes/wave, 32 lanes x uint2 per row ----------------
__global__ __launch_bounds__(256) void agg_mean_128(const uint2* __restrict__ xu2,
                                                    const int* __restrict__ row_start,
                                                    const int* __restrict__ deg,
                                                    const int* __restrict__ csr,
                                                    const float* __restrict__ inv_deg,
                                                    uint2* __restrict__ outu2) {
    int wave = threadIdx.x >> 6;
    int lane = threadIdx.x & 63;
    int half = lane >> 5, sub = lane & 31;
    int node = blockIdx.x * 8 + wave * 2 + half;
    int beg = row_start[node], end = beg + deg[node];
    float a0[8], a1[8], a2[8], a3[8];
#pragma unroll
    for (int k = 0; k < 8; k++) { a0[k] = 0.f; a1[k] = 0.f; a2[k] = 0.f; a3[k] = 0.f; }
    int j = beg;
    for (; j + 8 <= end; j += 8) {
        int idx[8];
#pragma unroll
        for (int k = 0; k < 8; k++) idx[k] = csr[j + k];
#pragma unroll
        for (int k = 0; k < 8; k++) {
            uint2 v = xu2[(size_t)idx[k] * 32 + sub];
            a0[k] += bflo(v.x); a1[k] += bfhi(v.x);
            a2[k] += bflo(v.y); a3[k] += bfhi(v.y);
        }
    }
    for (; j < end; j++) {
        uint2 v = xu2[(size_t)csr[j] * 32 + sub];
        a0[0] += bflo(v.x); a1[0] += bfhi(v.x);
        a2[0] += bflo(v.y); a3[0] += bfhi(v.y);
    }
    float sc = inv_deg[node];
    float r0 = (((a0[0] + a0[1]) + (a0[2] + a0[3])) + ((a0[4] + a0[5]) + (a0[6] + a0[7]))) * sc;
    float r1 = (((a1[0] + a1[1]) + (a1[2] + a1[3])) + ((a1[4] + a1[5]) + (a1[6] + a1[7]))) * sc;
    float r2 = (((a2[0] + a2[1]) + (a2[2] + a2[3])) + ((a2[4] + a2[5]) + (a2[6] + a2[7]))) * sc;
    float r3 = (((a3[0] + a3[1]) + (a3[2] + a3[3])) + ((a3[4] + a3[5]) + (a3[6] + a3[7]))) * sc;
    uint2 r;
    r.x = (uint32_t)f2bf(r0) | ((uint32_t)f2bf(r1) << 16);
    r.y = (uint32_t)f2bf(r2) | ((uint32_t)f2bf(r3) << 16);
    outu2[(size_t)node * 32 + sub] = r;
}

// final: out = mean_gather(t) + u, fp32 out; 2 nodes/wave, 32 lanes x uint2
__global__ __launch_bounds__(256) void agg_final_128(const uint2* __restrict__ tu2,
                                                     const int* __restrict__ row_start,
                                                     const int* __restrict__ deg,
                                                     const int* __restrict__ csr,
                                                     const float* __restrict__ inv_deg,
                                                     const float4* __restrict__ u4,
                                                     float4* __restrict__ out4) {
    int wave = threadIdx.x >> 6;
    int lane = threadIdx.x & 63;
    int half = lane >> 5, sub = lane & 31;
    int node = blockIdx.x * 8 + wave * 2 + half;
    int beg = row_start[node], end = beg + deg[node];
    float a0[8], a1[8], a2[8], a3[8];
#pragma unroll
    for (int k = 0; k < 8; k++) { a0[k] = 0.f; a1[k] = 0.f; a2[k] = 0.f; a3[k] = 0.f; }
    int j = beg;
    for (; j + 8 <= end; j += 8) {
        int idx[8];
#pragma unroll
        for (int k = 0; k < 8; k++) idx[k] = csr[j + k];
#pragma unroll
        for (int k = 0; k < 8; k++) {
            uint2 v = tu2[(size_t)idx[k] * 32 + sub];
            a0[k] += bflo(v.x); a1[k] += bfhi(v.x);
            a2[k] += bflo(v.y); a3[k] += bfhi(v.y);
        }
    }
    for (; j < end; j++) {
        uint2 v = tu2[(size_t)csr[j] * 32 + sub];
        a0[0] += bflo(v.x); a1[0] += bfhi(v.x);
        a2[0] += bflo(v.y); a3[0] += bfhi(v.y);
    }
    float sc = inv_deg[node];
    float4 uv = u4[(size_t)node * 32 + sub];
    float4 r;
    r.x = (((a0[0] + a0[1]) + (a0[2] + a0[3])) + ((a0[4] + a0[5]) + (a0[6] + a0[7]))) * sc + uv.x;
    r.y = (((a1[0] + a1[1]) + (a1[2] + a1[3])) + ((a1[4] + a1[5]) + (a1[6] + a1[7]))) * sc + uv.y;
    r.z = (((a2[0] + a2[1]) + (a2[2] + a2[3])) + ((a2[4] + a2[5]) + (a2[6] + a2[7]))) * sc + uv.z;
    r.w = (((a3[0] + a3[1]) + (a3[2] + a3[3])) + ((a3[4] + a3[5]) + (a3[6] + a3[7]))) * sc + uv.w;
    out4[(size_t)node * 32 + sub] = r;
}

// ---------------- layer-1 GEMM: B-fragments preloaded in registers ----------------
template <int K, int N>
__global__ __launch_bounds__(256) void gemm_dualA_breg(const uint16_t* __restrict__ A1,
                                                       const uint16_t* __restrict__ A2,
                                                       const uint16_t* __restrict__ W1sw,
                                                       const uint16_t* __restrict__ W2sw,
                                                       const uint16_t* __restrict__ bias,
                                                       uint16_t* __restrict__ C) {
    constexpr int NTF = N / 16, NTW = NTF / 4, KT = K / 32;
    int wave = threadIdx.x >> 6, lane = threadIdx.x & 63;
    int row0 = blockIdx.x * 64, bt = wave * NTW;
    int m = lane & 15, q = lane >> 4;
    int ar[4];
#pragma unroll
    for (int rf = 0; rf < 4; rf++) { int r = row0 + rf * 16 + m; ar[rf] = (r < NN) ? r : (NN - 1); }

    bf16x8 B1[KT][NTW], B2[KT][NTW];
#pragma unroll
    for (int kt = 0; kt < KT; kt++)
#pragma unroll
        for (int nt = 0; nt < NTW; nt++) {
            B1[kt][nt] = *(const bf16x8*)(W1sw + ((size_t)(kt * NTF + bt + nt)) * 512 + lane * 8);
            B2[kt][nt] = *(const bf16x8*)(W2sw + ((size_t)(kt * NTF + bt + nt)) * 512 + lane * 8);
        }

    f32x4 acc[4][NTW];
#pragma unroll
    for (int rf = 0; rf < 4; rf++)
#pragma unroll
        for (int nt = 0; nt < NTW; nt++)
#pragma unroll
            for (int i = 0; i < 4; i++) acc[rf][nt][i] = 0.f;

#pragma unroll
    for (int kt = 0; kt < KT; kt++) {
        bf16x8 a0 = *(const bf16x8*)(A1 + (size_t)ar[0] * K + kt * 32 + q * 8);
        bf16x8 a1 = *(const bf16x8*)(A1 + (size_t)ar[1] * K + kt * 32 + q * 8);
        bf16x8 a2 = *(const bf16x8*)(A1 + (size_t)ar[2] * K + kt * 32 + q * 8);
        bf16x8 a3 = *(const bf16x8*)(A1 + (size_t)ar[3] * K + kt * 32 + q * 8);
#pragma unroll
        for (int nt = 0; nt < NTW; nt++) {
            acc[0][nt] = __builtin_amdgcn_mfma_f32_16x16x32_bf16(a0, B1[kt][nt], acc[0][nt], 0, 0, 0);
            acc[1][nt] = __builtin_amdgcn_mfma_f32_16x16x32_bf16(a1, B1[kt][nt], acc[1][nt], 0, 0, 0);
            acc[2][nt] = __builtin_amdgcn_mfma_f32_16x16x32_bf16(a2, B1[kt][nt], acc[2][nt], 0, 0, 0);
            acc[3][nt] = __builtin_amdgcn_mfma_f32_16x16x32_bf16(a3, B1[kt][nt], acc[3][nt], 0, 0, 0);
        }
    }
#pragma unroll
    for (int kt = 0; kt < KT; kt++) {
        bf16x8 a0 = *(const bf16x8*)(A2 + (size_t)ar[0] * K + kt * 32 + q * 8);
        bf16x8 a1 = *(const bf16x8*)(A2 + (size_t)ar[1] * K + kt * 32 + q * 8);
        bf16x8 a2 = *(const bf16x8*)(A2 + (size_t)ar[2] * K + kt * 32 + q * 8);
        bf16x8 a3 = *(const bf16x8*)(A2 + (size_t)ar[3] * K + kt * 32 + q * 8);
#pragma unroll
        for (int nt = 0; nt < NTW; nt++) {
            acc[0][nt] = __builtin_amdgcn_mfma_f32_16x16x32_bf16(a0, B2[kt][nt], acc[0][nt], 0, 0, 0);
            acc[1][nt] = __builtin_amdgcn_mfma_f32_16x16x32_bf16(a1, B2[kt][nt], acc[1][nt], 0, 0, 0);
            acc[2][nt] = __builtin_amdgcn_mfma_f32_16x16x32_bf16(a2, B2[kt][nt], acc[2][nt], 0, 0, 0);
            acc[3][nt] = __builtin_amdgcn_mfma_f32_16x16x32_bf16(a3, B2[kt][nt], acc[3][nt], 0, 0, 0);
        }
    }

#pragma unroll
    for (int nt = 0; nt < NTW; nt++) {
        int col = (bt + nt) * 16 + m;
        float bv = bf2f(bias[col]);
#pragma unroll
        for (int rf = 0; rf < 4; rf++)
#pragma unroll
            for (int i = 0; i < 4; i++) {
                int r = row0 + rf * 16 + q * 4 + i;
                if (r < NN) {
                    float v = fmaxf(acc[rf][nt][i] + bv, 0.f);
                    C[(size_t)r * N + col] = f2bf(v);
                }
            }
    }
}

// ---------------- layer-2 GEMM (dual-B): t = A@W1 (bf16), u = A@W2 + bias (fp32) ----------------
template <int K, int N>
__global__ __launch_bounds__(256) void gemm_dualB_breg(const uint16_t* __restrict__ A,
                                                       const uint16_t* __restrict__ W1sw,
                                                       const uint16_t* __restrict__ W2sw,
                                                       const uint16_t* __restrict__ bias,
                                                       uint16_t* __restrict__ T,
                                                       float* __restrict__ U) {
    constexpr int NTF = N / 16, NTW = NTF / 4, KT = K / 32;
    int wave = threadIdx.x >> 6, lane = threadIdx.x & 63;
    int row0 = blockIdx.x * 64, bt = wave * NTW;
    int m = lane & 15, q = lane >> 4;
    int ar[4];
#pragma unroll
    for (int rf = 0; rf < 4; rf++) { int r = row0 + rf * 16 + m; ar[rf] = (r < NN) ? r : (NN - 1); }

    bf16x8 B1[KT][NTW], B2[KT][NTW];
#pragma unroll
    for (int kt = 0; kt < KT; kt++)
#pragma unroll
        for (int nt = 0; nt < NTW; nt++) {
            B1[kt][nt] = *(const bf16x8*)(W1sw + ((size_t)(kt * NTF + bt + nt)) * 512 + lane * 8);
            B2[kt][nt] = *(const bf16x8*)(W2sw + ((size_t)(kt * NTF + bt + nt)) * 512 + lane * 8);
        }

    f32x4 acc1[4][NTW], acc2[4][NTW];
#pragma unroll
    for (int rf = 0; rf < 4; rf++)
#pragma unroll
        for (int nt = 0; nt < NTW; nt++)
#pragma unroll
            for (int i = 0; i < 4; i++) { acc1[rf][nt][i] = 0.f; acc2[rf][nt][i] = 0.f; }

#pragma unroll
    for (int kt = 0; kt < KT; kt++) {
        bf16x8 a0 = *(const bf16x8*)(A + (size_t)ar[0] * K + kt * 32 + q * 8);
        bf16x8 a1 = *(const bf16x8*)(A + (size_t)ar[1] * K + kt * 32 + q * 8);
        bf16x8 a2 = *(const bf16x8*)(A + (size_t)ar[2] * K + kt * 32 + q * 8);
        bf16x8 a3 = *(const bf16x8*)(A + (size_t)ar[3] * K + kt * 32 + q * 8);
#pragma unroll
        for (int nt = 0; nt < NTW; nt++) {
            acc1[0][nt] = __builtin_amdgcn_mfma_f32_16x16x32_bf16(a0, B1[kt][nt], acc1[0][nt], 0, 0, 0);
            acc1[1][nt] = __builtin_amdgcn_mfma_f32_16x16x32_bf16(a1, B1[kt][nt], acc1[1][nt], 0, 0, 0);
            acc1[2][nt] = __builtin_amdgcn_mfma_f32_16x16x32_bf16(a2, B1[kt][nt], acc1[2][nt], 0, 0, 0);
            acc1[3][nt] = __builtin_amdgcn_mfma_f32_16x16x32_bf16(a3, B1[kt][nt], acc1[3][nt], 0, 0, 0);
            acc2[0][nt] = __builtin_amdgcn_mfma_f32_16x16x32_bf16(a0, B2[kt][nt], acc2[0][nt], 0, 0, 0);
            acc2[1][nt] = __builtin_amdgcn_mfma_f32_16x16x32_bf16(a1, B2[kt][nt], acc2[1][nt], 0, 0, 0);
            acc2[2][nt] = __builtin_amdgcn_mfma_f32_16x16x32_bf16(a2, B2[kt][nt], acc2[2][nt], 0, 0, 0);
            acc2[3][nt] = __builtin_amdgcn_mfma_f32_16x16x32_bf16(a3, B2[kt][nt], acc2[3][nt], 0, 0, 0);
        }
    }

#pragma unroll
    for (int nt = 0; nt < NTW; nt++) {
        int col = (bt + nt) * 16 + m;
        float bv = bf2f(bias[col]);
#pragma unroll
        for (int rf = 0; rf < 4; rf++)
#pragma unroll
            for (int i = 0; i < 4; i++) {
                int r = row0 + rf * 16 + q * 4 + i;
                if (r < NN) {
                    T[(size_t)r * N + col] = f2bf(acc1[rf][nt][i]);
                    U[(size_t)r * N + col] = acc2[rf][nt][i] + bv;
                }
            }
    }
}

extern "C" void kernel_launch(void* const* d_in, const int* in_sizes, int n_in,
                              void* d_out, int out_size, void* d_ws, size_t ws_size,
                              hipStream_t stream) {
    const void* x_raw  = d_in[0];
    const int*  ei     = (const int*)d_in[1];
    const void* W1l    = d_in[2];
    const void* b1     = d_in[3];
    const void* W1r    = d_in[4];
    const void* W2l    = d_in[5];
    const void* b2     = d_in[6];
    const void* W2r    = d_in[7];

    uint8_t* ws = (uint8_t*)d_ws;
    size_t off = 0;
    auto alloc = [&](size_t b) -> void* {
        void* p = ws + off;
        off += (b + 255) & ~(size_t)255;
        return p;
    };
    int*      flags       = (int*)alloc(256);
    int*      histM       = (int*)alloc((size_t)NB * NBLK * 4);
    int*      bucket_tot  = (int*)alloc((NB + 4) * 4);
    int*      bucket_base = (int*)alloc((NB + 4) * 4);
    int*      deg         = (int*)alloc((size_t)NN * 4);
    float*    inv_deg     = (float*)alloc((size_t)NN * 4);
    int*      row_start   = (int*)alloc((size_t)NN * 4);
    int*      csr         = (int*)alloc((size_t)NE * 4);
    uint32_t* xb          = (uint32_t*)alloc((size_t)NN * 64 * 4);
    uint16_t* bias_buf    = (uint16_t*)alloc(384 * 2);
    uint16_t* agg         = (uint16_t*)alloc((size_t)NN * 128 * 2);
    uint16_t* h           = (uint16_t*)alloc((size_t)NN * 256 * 2);
    uint16_t* t           = (uint16_t*)alloc((size_t)NN * 128 * 2);
    float*    u           = (float*)alloc((size_t)NN * 128 * 4);
    uint16_t* w1l_sw      = (uint16_t*)alloc(128 * 256 * 2);
    uint16_t* w1r_sw      = (uint16_t*)alloc(128 * 256 * 2);
    uint16_t* w2l_sw      = (uint16_t*)alloc(256 * 128 * 2);
    uint16_t* w2r_sw      = (uint16_t*)alloc(256 * 128 * 2);

    // staging aliases h (3.2 MB; fully consumed by build_csr before h is written)
    uint32_t* staging = (uint32_t*)h;

    detect<<<1, 256, 0, stream>>>((const uint32_t*)x_raw, ei, flags);

    hist_pass<<<NBLK, 256, 0, stream>>>(ei, flags, histM);
    scan_rows<<<NB, 512, 0, stream>>>(histM, bucket_tot);
    scan_tot<<<1, 256, 0, stream>>>(bucket_tot, bucket_base);
    scatter_pass<<<NBLK, 256, 0, stream>>>(ei, flags, histM, bucket_base, staging);
    build_csr<<<NB, 256, 0, stream>>>(staging, bucket_base, row_start, deg, inv_deg, csr);

    norm_x<<<(NN * 64 + 255) / 256, 256, 0, stream>>>(x_raw, flags, xb);
    norm_weights_sw<<<66, 256, 0, stream>>>(W1l, b1, W1r, W2l, b2, W2r, flags,
                                            w1l_sw, w1r_sw, w2l_sw, w2r_sw, bias_buf);

    // layer 1: agg = A·x ; h = relu(agg@W1l + x@W1r + b1)
    agg_mean_128<<<(NN + 7) / 8, 256, 0, stream>>>((const uint2*)xb, row_start, deg, csr, inv_deg, (uint2*)agg);
    gemm_dualA_breg<128, 256><<<(NN + 63) / 64, 256, 0, stream>>>(agg, (const uint16_t*)xb,
                                                                  w1l_sw, w1r_sw, bias_buf, h);
    // layer 2: t = h@W2l, u = h@W2r + b2 ; out = A·t + u
    gemm_dualB_breg<256, 128><<<(NN + 63) / 64, 256, 0, stream>>>(h, w2l_sw, w2r_sw, bias_buf + 256, t, u);
    agg_final_128<<<(NN + 7) / 8, 256, 0, stream>>>((const uint2*)t, row_start, deg, csr, inv_deg,
                                                    (const float4*)u, (float4*)d_out);
}